// Round 18
// baseline (49.716 us; speedup 1.0000x reference)
//
#include <hip/hip_runtime.h>
#include <math.h>

#define NIMG 24        // B*C = 8*3
#define H    256
#define W    256
#define NPIX (H * W)
#define NROWS (NIMG * H)          // 6144
#define CPB  16                   // columns per K2 tile
#define NBLK2 (NIMG * (W / CPB))  // 384
#define LDP2 17                   // padded LDS row stride (floats)
#define BIGI 1000000
#define CAPS 1024                 // int16 sentinel for capped g (=1e6)

// ---------------------------------------------------------------------------
// MEASUREMENT ROUND (r18): same r17-validated kernels, launched as
// K1, K1, K2, K2(dummy), K2(dummy) to split T_K1 vs T_K2 from one number:
//   dur - 3 = 2*T_K1 + 3*T_K2 ;  T_K1 + T_K2 = 20.3 (r17 calibration)
//   => T_K1 = 63.9 - dur ; T_K2 = dur - 43.6
// All replicas are idempotent (identical f rewrite; dummy atomic target in
// ws) -> output unchanged, absmax 0.
// ---------------------------------------------------------------------------

// K1: 384 blocks x 256 thr. Ballot O(1) row EDT (r11-validated bit-exact),
// int16 output (r13-validated). Zeroes out[0] (published at node boundary).
__global__ __launch_bounds__(256)
void edt_rows_kernel(const int* __restrict__ tgt,
                     short* __restrict__ f,
                     float* __restrict__ out) {
    if (blockIdx.x == 0 && threadIdx.x == 0) out[0] = 0.0f;

    const int lane = threadIdx.x & 63;
    const int wid  = threadIdx.x >> 6;        // 0..3
    const int gw   = blockIdx.x * 4 + wid;    // 0..1535
    const int c0   = lane << 2;

    int4 tvs[4];
#pragma unroll
    for (int s = 0; s < 4; ++s)
        tvs[s] = ((const int4*)(tgt + (((gw << 2) + s) << 8)))[lane];

#pragma unroll
    for (int s = 0; s < 4; ++s) {
        const int row = (gw << 2) + s;
        const int4 tv = tvs[s];

        const int prevw = __shfl_up(tv.w, 1, 64);
        const bool ch0 = (lane > 0) && ((tv.x != 0) != (prevw != 0));
        const bool ch1 = (tv.y != 0) != (tv.x != 0);
        const bool ch2 = (tv.z != 0) != (tv.y != 0);
        const bool ch3 = (tv.w != 0) != (tv.z != 0);

        const int a0 = ch0 ? c0     : -BIGI;
        const int a1 = ch1 ? c0 + 1 : a0;
        const int a2 = ch2 ? c0 + 2 : a1;
        const int a3 = ch3 ? c0 + 3 : a2;
        const int rb3 = ch3 ? c0 + 3 : BIGI;
        const int rb2 = ch2 ? c0 + 2 : rb3;
        const int rb1 = ch1 ? c0 + 1 : rb2;
        const int rb0 = ch0 ? c0     : rb1;

        const unsigned long long mask = __ballot(ch0 | ch1 | ch2 | ch3);
        const unsigned long long lowm = mask & ((1ULL << lane) - 1ULL);
        const unsigned long long him  = (lane < 63) ? (mask >> (lane + 1)) : 0ULL;

        const int plane = 63 - __builtin_clzll(lowm | 1ULL);
        const int sh_a  = __shfl(a3, plane & 63, 64);
        const int ex    = (lowm != 0ULL) ? sh_a : -BIGI;

        const int qlane = lane + 1 +
            (int)__builtin_ctzll(him | 0x8000000000000000ULL);
        const int sh_r  = __shfl(rb0, qlane & 63, 64);
        const int exr   = (him != 0ULL) ? sh_r : BIGI;

        const int s0 = (ex > a0) ? ex : a0;
        const int s1 = (ex > a1) ? ex : a1;
        const int s2 = (ex > a2) ? ex : a2;
        const int s3 = (ex > a3) ? ex : a3;
        const int n0 = (rb1 < exr) ? rb1 : exr;
        const int n1 = (rb2 < exr) ? rb2 : exr;
        const int n2 = (rb3 < exr) ? rb3 : exr;
        const int n3 = exr;

        auto gcalc = [](int c, int ss, int nn) -> int {
            int dp = c - ss + 1;
            int dn = nn - c;
            int g = dp < dn ? dp : dn;
            return (g < BIGI) ? g : CAPS;
        };
        const int g0 = gcalc(c0,     s0, n0);
        const int g1 = gcalc(c0 + 1, s1, n1);
        const int g2 = gcalc(c0 + 2, s2, n2);
        const int g3 = gcalc(c0 + 3, s3, n3);

        short4 o;
        o.x = (short)((tv.x != 0) ? g0 : -g0);
        o.y = (short)((tv.y != 0) ? g1 : -g1);
        o.z = (short)((tv.z != 0) ? g2 : -g2);
        o.w = (short)((tv.w != 0) ? g3 : -g3);
        ((short4*)(f + (row << 8)))[lane] = o;
    }
}

// K2: 384 blocks x 512 thr, tile = (img, 16-col group). r15/r17-validated
// bit-exact window min-plus + sigmoid + double reduce + fp32 atomic.
__global__ __launch_bounds__(512)
void edt_cols_kernel(const short* __restrict__ f,
                     const float* __restrict__ pred,
                     float* __restrict__ out) {
    const int bid  = blockIdx.x;          // img*16 + grp
    const int img  = bid >> 4;
    const int j0   = (bid & 15) << 4;
    const int t    = threadIdx.x;
    const int lane = t & 63;
    const int wid  = t >> 6;

    __shared__ float sf[H][LDP2];
    __shared__ double wsum[8];
    __shared__ int nonempty;
    if (t == 0) nonempty = 0;
    __syncthreads();

    {
        const int row = t >> 1;
        const int q   = (t & 1) << 3;
        const int4 rv = *(const int4*)(f + (img << 16) + (row << 8) + j0 + q);
        const short* sv = (const short*)&rv;
        bool ne = false;
#pragma unroll
        for (int j = 0; j < 8; ++j) {
            const int v = sv[j];
            ne = ne || (v != -CAPS);
            float g = (float)v;
            if (v == CAPS)  g =  1.0e6f;
            if (v == -CAPS) g = -1.0e6f;
            sf[row][q + j] = g;
        }
        if (ne) nonempty = 1;
    }

    const int c  = t & 15;
    const int r0 = (t >> 4) << 3;
    float pf[8];
#pragma unroll
    for (int ii = 0; ii < 8; ++ii)
        pf[ii] = pred[(img << 16) + ((r0 + ii) << 8) + j0 + c];

    __syncthreads();
    const int flag = nonempty;

    double acc = 0.0;
#pragma unroll
    for (int ii = 0; ii < 8; ++ii) {
        const int i = r0 + ii;
        const float fv = sf[i][c];
        const bool  m  = fv > 0.0f;
        const float sgn = m ? 1.0f : -1.0f;
        const float gi = fabsf(fv);
        const int  gii = (int)gi;
        int lo = i - gii; lo = lo > 0 ? lo : 0;
        int hi = i + gii; hi = hi < (H - 1) ? hi : (H - 1);

        float dm = 3.0e38f;
        float dk = (float)(i - lo);
        for (int k = lo; k <= hi; ++k) {
            const float g = fmaxf(sgn * sf[k][c], 0.0f);
            dm = fminf(dm, g * g + dk * dk);
            dk -= 1.0f;
        }

        float d = m ? sqrtf(dm) : -sqrtf(dm);
        if (!flag) d = 0.0f;
        const float sig = 1.0f / (1.0f + expf(-pf[ii]));
        acc += (double)sig * (double)d;
    }

#pragma unroll
    for (int off = 32; off > 0; off >>= 1) acc += __shfl_down(acc, off, 64);
    if (lane == 0) wsum[wid] = acc;
    __syncthreads();
    if (t == 0) {
        double s = 0.0;
#pragma unroll
        for (int w = 0; w < 8; ++w) s += wsum[w];
        atomicAdd(out, (float)(s * (1.0 / (double)(NIMG * NPIX))));
    }
}

extern "C" void kernel_launch(void* const* d_in, const int* in_sizes, int n_in,
                              void* d_out, int out_size, void* d_ws, size_t ws_size,
                              hipStream_t stream) {
    const float* pred = (const float*)d_in[0];
    const int*   tgt  = (const int*)d_in[1];
    float* out = (float*)d_out;

    char* ws = (char*)d_ws;
    const size_t fbytes = (size_t)NIMG * NPIX * sizeof(short);  // 3,145,728 B
    short* fbuf  = (short*)ws;
    float* dummy = (float*)(ws + fbytes);   // scratch atomic target (poisoned, unused)

    // --- measurement sequence: 2x K1, 1x real K2, 2x dummy K2 ---
    edt_rows_kernel<<<384, 256, 0, stream>>>(tgt, fbuf, out);
    edt_rows_kernel<<<384, 256, 0, stream>>>(tgt, fbuf, out);      // replica (idempotent)
    edt_cols_kernel<<<NBLK2, 512, 0, stream>>>(fbuf, pred, out);   // real
    edt_cols_kernel<<<NBLK2, 512, 0, stream>>>(fbuf, pred, dummy); // replica
    edt_cols_kernel<<<NBLK2, 512, 0, stream>>>(fbuf, pred, dummy); // replica
}

// Round 19
// 23.336 us; speedup vs baseline: 2.1304x; 2.1304x over previous
//
#include <hip/hip_runtime.h>
#include <math.h>

#define NIMG 24        // B*C = 8*3
#define H    256
#define W    256
#define NPIX (H * W)
#define NROWS (NIMG * H)          // 6144
#define CPB  16                   // columns per K2 tile
#define NBLK2 (NIMG * (W / CPB))  // 384
#define LDP2 17                   // padded LDS row stride (floats)
#define BIGI 1000000
#define CAPS 1024                 // int16 sentinel for capped g (=1e6)

// ---------------------------------------------------------------------------
// K1 v2 (r19): ZERO cross-lane ops — r18 measurement isolated K1 at
// ~14-17us, invariant to occupancy; the serial shfl_up/ballot/bpermute
// chain (~3 dependent LDS-xlane ops per row) at 1.5 waves/SIMD was the
// latency wall. New scheme, 384 blocks x 256 thr, thread = (row, 16-col
// chunk):
//   phase 1: 4x int4 loads + boundary int -> 16 change bits -> ushort to
//            LDS (row-major 256-bit change mask per row).
//   phase 2: read own row's 4 mask words (broadcast within row group,
//            conflict-free across rows), compute initial last/next via
//            masked clz/ctz (static word regs), then 16-px incremental
//            walk. Same integer arithmetic as the r11-validated ballot
//            version (dp = j-last+1, dn = n-j, g = min(dp,dn), cap ->
//            CAPS sentinel) -> bit-exact by construction. Sign from the
//            int4s still in registers. int16 output (r13-validated).
// Thread (0,0) zeroes out[0] (published to K2's atomics at node boundary).
// ---------------------------------------------------------------------------
__global__ __launch_bounds__(256)
void edt_rows_kernel(const int* __restrict__ tgt,
                     short* __restrict__ f,
                     float* __restrict__ out) {
    if (blockIdx.x == 0 && threadIdx.x == 0) out[0] = 0.0f;

    const int t    = threadIdx.x;
    const int rloc = t >> 4;                  // local row 0..15
    const int ck   = t & 15;                  // 16-col chunk 0..15
    const int row  = blockIdx.x * 16 + rloc;  // global row 0..6143
    const int j0   = ck << 4;
    const int base = (row << 8) + j0;

    __shared__ unsigned long long m[16][4];   // per-row 256-bit change masks

    // ---------------- phase 1: build change bits ----------------
    const int4* rp = (const int4*)(tgt + base);
    const int4 v0 = rp[0], v1 = rp[1], v2 = rp[2], v3 = rp[3];
    const int prevv = (ck > 0) ? tgt[base - 1] : 0;

    int va[16];
    *(int4*)&va[0]  = v0;  *(int4*)&va[4]  = v1;
    *(int4*)&va[8]  = v2;  *(int4*)&va[12] = v3;

    unsigned int bits = 0;
    {
        bool pc = (prevv != 0);
#pragma unroll
        for (int i = 0; i < 16; ++i) {
            const bool c = (va[i] != 0);
            if (c != pc) bits |= (1u << i);
            pc = c;
        }
        if (ck == 0) bits &= ~1u;             // col 0 has no predecessor
    }
    ((unsigned short*)m)[(rloc << 4) + ck] = (unsigned short)bits;
    __syncthreads();

    // ---------------- phase 2: per-pixel distances from mask ----------------
    const unsigned long long M0 = m[rloc][0], M1 = m[rloc][1];
    const unsigned long long M2 = m[rloc][2], M3 = m[rloc][3];
    const int wlo = ck >> 2;
    const int blo = (ck & 3) << 4;
    const int bhi = blo + 16;

    // last change at position < j0 (else -BIGI)
    const unsigned long long pm  = blo ? ((1ULL << blo) - 1ULL) : 0ULL;
    const unsigned long long lm0 = (wlo > 0) ? ~0ULL : pm;
    const unsigned long long lm1 = (wlo > 1) ? ~0ULL : ((wlo == 1) ? pm : 0ULL);
    const unsigned long long lm2 = (wlo > 2) ? ~0ULL : ((wlo == 2) ? pm : 0ULL);
    const unsigned long long lm3 = (wlo == 3) ? pm : 0ULL;
    int last = -BIGI;
    {
        unsigned long long x;
        x = M0 & lm0; if (x) last = 63 - __builtin_clzll(x);
        x = M1 & lm1; if (x) last = 127 - __builtin_clzll(x);
        x = M2 & lm2; if (x) last = 191 - __builtin_clzll(x);
        x = M3 & lm3; if (x) last = 255 - __builtin_clzll(x);
    }

    // first change at position >= j0+16 (else BIGI)
    const unsigned long long sm  = (bhi == 64) ? 0ULL : ~((1ULL << bhi) - 1ULL);
    const unsigned long long hm0 = (wlo == 0) ? sm : 0ULL;
    const unsigned long long hm1 = (wlo < 1) ? ~0ULL : ((wlo == 1) ? sm : 0ULL);
    const unsigned long long hm2 = (wlo < 2) ? ~0ULL : ((wlo == 2) ? sm : 0ULL);
    const unsigned long long hm3 = (wlo < 3) ? ~0ULL : sm;
    int nxt_hi = BIGI;
    {
        unsigned long long x;
        x = M3 & hm3; if (x) nxt_hi = 192 + __builtin_ctzll(x);
        x = M2 & hm2; if (x) nxt_hi = 128 + __builtin_ctzll(x);
        x = M1 & hm1; if (x) nxt_hi =  64 + __builtin_ctzll(x);
        x = M0 & hm0; if (x) nxt_hi =       __builtin_ctzll(x);
    }

    // 16-pixel incremental walk (identical int arithmetic to r11's gcalc)
    short os[16];
    unsigned int rem = bits;
#pragma unroll
    for (int i = 0; i < 16; ++i) {
        const int j = j0 + i;
        if (rem & 1u) last = j;               // change AT j -> run starts here
        rem >>= 1;
        const int n  = rem ? (j + 1 + __builtin_ctz(rem)) : nxt_hi;
        const int dp = j - last + 1;
        const int dn = n - j;
        int g = dp < dn ? dp : dn;
        g = (g < BIGI) ? g : CAPS;            // cap sentinel (r13-validated)
        os[i] = (short)((va[i] != 0) ? g : -g);
    }

    // pack 16 shorts -> two int4 stores (32B contiguous per thread)
    int pk[8];
#pragma unroll
    for (int i = 0; i < 8; ++i)
        pk[i] = (int)((unsigned short)os[2 * i] |
                      ((unsigned int)(unsigned short)os[2 * i + 1] << 16));
    int4* op = (int4*)(f + base);
    op[0] = make_int4(pk[0], pk[1], pk[2], pk[3]);
    op[1] = make_int4(pk[4], pk[5], pk[6], pk[7]);
}

// ---------------------------------------------------------------------------
// K2: unchanged from r17 (clean A/B on K1). 384 blocks x 512 thr, tile =
// (img, 16-col group). int16 decode (r13-validated), empty-mask flag from
// cap markers, window-bounded exact min-plus (bit-exact vs reference),
// pred prefetch, 8-wave fixed-order double reduce, fp32 atomic finalize
// (r16-validated; rounding ~1e-8 << 1.2e-5 threshold).
// ---------------------------------------------------------------------------
__global__ __launch_bounds__(512)
void edt_cols_kernel(const short* __restrict__ f,
                     const float* __restrict__ pred,
                     float* __restrict__ out) {
    const int bid  = blockIdx.x;          // img*16 + grp
    const int img  = bid >> 4;
    const int j0   = (bid & 15) << 4;
    const int t    = threadIdx.x;
    const int lane = t & 63;
    const int wid  = t >> 6;

    __shared__ float sf[H][LDP2];
    __shared__ double wsum[8];
    __shared__ int nonempty;
    if (t == 0) nonempty = 0;
    __syncthreads();

    {
        const int row = t >> 1;
        const int q   = (t & 1) << 3;
        const int4 rv = *(const int4*)(f + (img << 16) + (row << 8) + j0 + q);
        const short* sv = (const short*)&rv;
        bool ne = false;
#pragma unroll
        for (int j = 0; j < 8; ++j) {
            const int v = sv[j];
            ne = ne || (v != -CAPS);
            float g = (float)v;
            if (v == CAPS)  g =  1.0e6f;
            if (v == -CAPS) g = -1.0e6f;
            sf[row][q + j] = g;
        }
        if (ne) nonempty = 1;             // benign race, all write 1
    }

    const int c  = t & 15;
    const int r0 = (t >> 4) << 3;
    float pf[8];
#pragma unroll
    for (int ii = 0; ii < 8; ++ii)
        pf[ii] = pred[(img << 16) + ((r0 + ii) << 8) + j0 + c];

    __syncthreads();
    const int flag = nonempty;            // exact: mask.sum() != 0

    double acc = 0.0;
#pragma unroll
    for (int ii = 0; ii < 8; ++ii) {
        const int i = r0 + ii;
        const float fv = sf[i][c];
        const bool  m  = fv > 0.0f;       // sign(f) = pixel polarity
        const float sgn = m ? 1.0f : -1.0f;
        const float gi = fabsf(fv);
        const int  gii = (int)gi;
        int lo = i - gii; lo = lo > 0 ? lo : 0;
        int hi = i + gii; hi = hi < (H - 1) ? hi : (H - 1);

        float dm = 3.0e38f;
        float dk = (float)(i - lo);
        for (int k = lo; k <= hi; ++k) {
            const float g = fmaxf(sgn * sf[k][c], 0.0f);  // needed polarity
            dm = fminf(dm, g * g + dk * dk);
            dk -= 1.0f;
        }

        float d = m ? sqrtf(dm) : -sqrtf(dm);
        if (!flag) d = 0.0f;
        const float sig = 1.0f / (1.0f + expf(-pf[ii]));
        acc += (double)sig * (double)d;
    }

#pragma unroll
    for (int off = 32; off > 0; off >>= 1) acc += __shfl_down(acc, off, 64);
    if (lane == 0) wsum[wid] = acc;
    __syncthreads();
    if (t == 0) {
        double s = 0.0;
#pragma unroll
        for (int w = 0; w < 8; ++w) s += wsum[w];
        atomicAdd(out, (float)(s * (1.0 / (double)(NIMG * NPIX))));
    }
}

extern "C" void kernel_launch(void* const* d_in, const int* in_sizes, int n_in,
                              void* d_out, int out_size, void* d_ws, size_t ws_size,
                              hipStream_t stream) {
    const float* pred = (const float*)d_in[0];
    const int*   tgt  = (const int*)d_in[1];
    float* out = (float*)d_out;

    short* fbuf = (short*)d_ws;           // 3,145,728 B intermediate

    edt_rows_kernel<<<384, 256, 0, stream>>>(tgt, fbuf, out);
    edt_cols_kernel<<<NBLK2, 512, 0, stream>>>(fbuf, pred, out);
}